// Round 8
// baseline (713.875 us; speedup 1.0000x reference)
//
#include <hip/hip_runtime.h>

// HeteroSAGE on MI355X — round 11: gather-into-GEMM fusion + launch merging.
// R10 post-mortem: F1/F2 fusion works (675us), fused2 control unchanged.
// Remaining ~460us is spread across gathers/scan/small-GEMM tails/launch
// gaps. This round: (1) fusedU2 = gather_mean fused into F2's stage-1 A
// operand (mean rows gathered straight into the LDS tile; mean_card/
// mean_merch buffers deleted, -31MB); (2) card+merch merged into single
// launches (fusedE_both / fusedU2_both); (3) scan2 at 8 items/thread
// (49 -> 7 barrier rounds). 13 launches -> 9. fused2 (A/B) untouched.

#define N_TX    200000
#define N_CARD  50000
#define N_MERCH 10000
#define NE      200000

typedef __attribute__((ext_vector_type(8))) short short8;
typedef __attribute__((ext_vector_type(4))) float f32x4;

__device__ inline unsigned short f2b(float f) {
    unsigned u = __builtin_bit_cast(unsigned, f);
    unsigned r = (u + 0x7fffu + ((u >> 16) & 1u)) >> 16;   // RNE
    return (unsigned short)r;
}
__device__ inline float b2f(unsigned short s) {
    return __builtin_bit_cast(float, (unsigned)s << 16);
}

// ---------------------------------------------------------------------------
// Fused two-GEMM kernel (R8-proven, UNTOUCHED). 64-row tiles, 4 waves.
// mode A (OUT0 != null):  h0 = relu(A@W1 + b1)        -> store OUT0 (bf16)
//                         out = relu(h0@W2 + b2 + P1[I1]+P2[I2]) -> OUT1 bf16
// mode B (OUT0 == null):  h  = relu(A@W1 + b1 + P1[I1]+P2[I2])   (LDS only)
//                         out[r] = relu(h@W2 + b2) . h2w + h2b   -> OUT1 f32
__global__ __launch_bounds__(256, 3) void fused2(
    const void* __restrict__ A, int a_f32,
    const unsigned short* __restrict__ W1T, const float* __restrict__ b1,
    const unsigned short* __restrict__ W2T, const float* __restrict__ b2,
    const unsigned short* __restrict__ P1, const int* __restrict__ I1,
    const unsigned short* __restrict__ P2, const int* __restrict__ I2,
    unsigned short* __restrict__ OUT0,
    const float* __restrict__ h2w, const float* __restrict__ h2b,
    void* __restrict__ OUT1, int M)
{
    __shared__ float Tf[64 * 132];            // fp32 transpose tile
    __shared__ unsigned short Tb[64 * 136];   // bf16 stage-2 A tile
    const int tid  = threadIdx.x;
    const int wave = tid >> 6;
    const int lane = tid & 63;
    const int quad = lane >> 4;
    const int l15  = lane & 15;
    const int base = blockIdx.x * 64;
    const int rgrp = tid >> 4;                // 0..15: row-pass row group
    const int c0   = l15 * 8;                 // row-pass column block
    const bool modeA = (OUT0 != nullptr);

    int idx1[4], idx2[4];
#pragma unroll
    for (int p = 0; p < 4; ++p) {
        int r = base + p * 16 + rgrp;
        int rc = (r < M) ? r : 0;
        idx1[p] = I1 ? I1[rc] : 0;
        idx2[p] = I2 ? I2[rc] : 0;
    }

    short8 af[4];
    {
        int r = base + wave * 16 + l15;
        int rc = (r < M) ? r : 0;
        if (a_f32) {
            const float* ap = (const float*)A + (size_t)rc * 128 + quad * 8;
#pragma unroll
            for (int kk = 0; kk < 4; ++kk) {
                float4 u = *reinterpret_cast<const float4*>(ap + kk * 32);
                float4 v = *reinterpret_cast<const float4*>(ap + kk * 32 + 4);
                short8 t;
                t[0] = (short)f2b(u.x); t[1] = (short)f2b(u.y);
                t[2] = (short)f2b(u.z); t[3] = (short)f2b(u.w);
                t[4] = (short)f2b(v.x); t[5] = (short)f2b(v.y);
                t[6] = (short)f2b(v.z); t[7] = (short)f2b(v.w);
                af[kk] = t;
            }
        } else {
            const unsigned short* ap =
                (const unsigned short*)A + (size_t)rc * 128 + quad * 8;
#pragma unroll
            for (int kk = 0; kk < 4; ++kk)
                af[kk] = *reinterpret_cast<const short8*>(ap + kk * 32);
        }
    }

    f32x4 acc[8];
#pragma unroll
    for (int nt = 0; nt < 8; ++nt) acc[nt] = (f32x4){0.f, 0.f, 0.f, 0.f};
#pragma unroll
    for (int nt = 0; nt < 8; ++nt) {
        const unsigned short* bp = W1T + (nt * 16 + l15) * 128 + quad * 8;
#pragma unroll
        for (int kk = 0; kk < 4; ++kk) {
            short8 bf = *reinterpret_cast<const short8*>(bp + kk * 32);
            acc[nt] = __builtin_amdgcn_mfma_f32_16x16x32_bf16(
                af[kk], bf, acc[nt], 0, 0, 0);
        }
    }

    short8 p1v[4], p2v[4];
    if (P1) {
#pragma unroll
        for (int p = 0; p < 4; ++p)
            p1v[p] = *reinterpret_cast<const short8*>(
                P1 + (size_t)idx1[p] * 128 + c0);
    }
    if (P2) {
#pragma unroll
        for (int p = 0; p < 4; ++p)
            p2v[p] = *reinterpret_cast<const short8*>(
                P2 + (size_t)idx2[p] * 128 + c0);
    }

    const int lrow0 = wave * 16 + quad * 4;
    if (modeA) {
#pragma unroll
        for (int nt = 0; nt < 8; ++nt) {
            float bb = b1 ? b1[nt * 16 + l15] : 0.f;
#pragma unroll
            for (int reg = 0; reg < 4; ++reg)
                Tb[(lrow0 + reg) * 136 + nt * 16 + l15] =
                    f2b(fmaxf(acc[nt][reg] + bb, 0.f));
        }
    } else {
#pragma unroll
        for (int nt = 0; nt < 8; ++nt)
#pragma unroll
            for (int reg = 0; reg < 4; ++reg)
                Tf[(lrow0 + reg) * 132 + nt * 16 + l15] = acc[nt][reg];
    }
    __syncthreads();

    if (modeA) {
#pragma unroll
        for (int p = 0; p < 4; ++p) {
            const int rloc = p * 16 + rgrp;
            const int r = base + rloc;
            if (r < M) {
                short8 hv = *reinterpret_cast<const short8*>(&Tb[rloc * 136 + c0]);
                *reinterpret_cast<short8*>(OUT0 + (size_t)r * 128 + c0) = hv;
            }
        }
    } else {
        float b1r[8];
#pragma unroll
        for (int j = 0; j < 8; ++j) b1r[j] = b1 ? b1[c0 + j] : 0.f;
#pragma unroll
        for (int p = 0; p < 4; ++p) {
            const int rloc = p * 16 + rgrp;
            float4 u = *reinterpret_cast<const float4*>(&Tf[rloc * 132 + c0]);
            float4 v = *reinterpret_cast<const float4*>(&Tf[rloc * 132 + c0 + 4]);
            float o[8] = {u.x, u.y, u.z, u.w, v.x, v.y, v.z, v.w};
            short8 ov;
#pragma unroll
            for (int j = 0; j < 8; ++j) {
                float t = o[j] + b1r[j];
                if (P1) t += b2f((unsigned short)p1v[p][j]);
                if (P2) t += b2f((unsigned short)p2v[p][j]);
                ov[j] = (short)f2b(fmaxf(t, 0.f));
            }
            *reinterpret_cast<short8*>(&Tb[rloc * 136 + c0]) = ov;
        }
        __syncthreads();
    }

    short8 af2[4];
#pragma unroll
    for (int kk = 0; kk < 4; ++kk)
        af2[kk] = *reinterpret_cast<const short8*>(
            &Tb[(wave * 16 + l15) * 136 + quad * 8 + kk * 32]);

    f32x4 acc2[8];
#pragma unroll
    for (int nt = 0; nt < 8; ++nt) acc2[nt] = (f32x4){0.f, 0.f, 0.f, 0.f};
#pragma unroll
    for (int nt = 0; nt < 8; ++nt) {
        const unsigned short* bp = W2T + (nt * 16 + l15) * 128 + quad * 8;
#pragma unroll
        for (int kk = 0; kk < 4; ++kk) {
            short8 bf = *reinterpret_cast<const short8*>(bp + kk * 32);
            acc2[nt] = __builtin_amdgcn_mfma_f32_16x16x32_bf16(
                af2[kk], bf, acc2[nt], 0, 0, 0);
        }
    }

    if (!modeA) {
        float hsum[4] = {0.f, 0.f, 0.f, 0.f};
#pragma unroll
        for (int nt = 0; nt < 8; ++nt) {
            float bb = b2 ? b2[nt * 16 + l15] : 0.f;
            float w = h2w[nt * 16 + l15];
#pragma unroll
            for (int reg = 0; reg < 4; ++reg) {
                float o = fmaxf(acc2[nt][reg] + bb, 0.f);
                hsum[reg] += o * w;
            }
        }
        float* OUTf = (float*)OUT1;
#pragma unroll
        for (int reg = 0; reg < 4; ++reg) {
            float h = hsum[reg];
            h += __shfl_xor(h, 1);
            h += __shfl_xor(h, 2);
            h += __shfl_xor(h, 4);
            h += __shfl_xor(h, 8);
            int r = base + wave * 16 + quad * 4 + reg;
            if (l15 == 0 && r < M) OUTf[r] = h + h2b[0];
        }
    } else {
#pragma unroll
        for (int nt = 0; nt < 8; ++nt)
#pragma unroll
            for (int reg = 0; reg < 4; ++reg)
                Tf[(lrow0 + reg) * 132 + nt * 16 + l15] = acc2[nt][reg];
        __syncthreads();
        float b2r[8];
#pragma unroll
        for (int j = 0; j < 8; ++j) b2r[j] = b2 ? b2[c0 + j] : 0.f;
        unsigned short* OB = (unsigned short*)OUT1;
#pragma unroll
        for (int p = 0; p < 4; ++p) {
            const int rloc = p * 16 + rgrp;
            const int r = base + rloc;
            float4 u = *reinterpret_cast<const float4*>(&Tf[rloc * 132 + c0]);
            float4 v = *reinterpret_cast<const float4*>(&Tf[rloc * 132 + c0 + 4]);
            float o[8] = {u.x, u.y, u.z, u.w, v.x, v.y, v.z, v.w};
            short8 ov;
#pragma unroll
            for (int j = 0; j < 8; ++j) {
                float t = o[j] + b2r[j];
                if (P1) t += b2f((unsigned short)p1v[p][j]);
                if (P2) t += b2f((unsigned short)p2v[p][j]);
                ov[j] = (short)f2b(fmaxf(t, 0.f));
            }
            if (r < M)
                *reinterpret_cast<short8*>(OB + (size_t)r * 128 + c0) = ov;
        }
    }
}

// ---------------------------------------------------------------------------
// F1 both types in one launch: h0 = A(f32,[M][64])@W1T + b1 -> OUT0;
// p1 = h0@W2T -> OUT1. blockIdx < nbc -> card params, else merch.
__global__ __launch_bounds__(256, 3) void fusedE_both(
    const float* __restrict__ Ac, const unsigned short* __restrict__ W1Tc,
    const float* __restrict__ b1c, const unsigned short* __restrict__ W2Tc,
    unsigned short* __restrict__ OUT0c, unsigned short* __restrict__ OUT1c,
    int Mc, int nbc,
    const float* __restrict__ Am, const unsigned short* __restrict__ W1Tm,
    const float* __restrict__ b1m, const unsigned short* __restrict__ W2Tm,
    unsigned short* __restrict__ OUT0m, unsigned short* __restrict__ OUT1m,
    int Mm)
{
    __shared__ float Tf[64 * 132];
    __shared__ unsigned short Tb[64 * 136];
    const bool isC = (int)blockIdx.x < nbc;
    const int bx   = isC ? blockIdx.x : blockIdx.x - nbc;
    const float* A = isC ? Ac : Am;
    const unsigned short* W1T = isC ? W1Tc : W1Tm;
    const float* b1 = isC ? b1c : b1m;
    const unsigned short* W2T = isC ? W2Tc : W2Tm;
    unsigned short* OUT0 = isC ? OUT0c : OUT0m;
    unsigned short* OUT1 = isC ? OUT1c : OUT1m;
    const int M = isC ? Mc : Mm;

    const int tid  = threadIdx.x;
    const int wave = tid >> 6;
    const int lane = tid & 63;
    const int quad = lane >> 4;
    const int l15  = lane & 15;
    const int base = bx * 64;
    const int rgrp = tid >> 4;
    const int c0   = l15 * 8;

    // stage 1: K=64
    short8 af[2];
    {
        int r = base + wave * 16 + l15;
        int rc = (r < M) ? r : 0;
        const float* ap = A + (size_t)rc * 64 + quad * 8;
#pragma unroll
        for (int kk = 0; kk < 2; ++kk) {
            float4 u = *reinterpret_cast<const float4*>(ap + kk * 32);
            float4 v = *reinterpret_cast<const float4*>(ap + kk * 32 + 4);
            short8 t;
            t[0] = (short)f2b(u.x); t[1] = (short)f2b(u.y);
            t[2] = (short)f2b(u.z); t[3] = (short)f2b(u.w);
            t[4] = (short)f2b(v.x); t[5] = (short)f2b(v.y);
            t[6] = (short)f2b(v.z); t[7] = (short)f2b(v.w);
            af[kk] = t;
        }
    }

    f32x4 acc[8];
#pragma unroll
    for (int nt = 0; nt < 8; ++nt) acc[nt] = (f32x4){0.f, 0.f, 0.f, 0.f};
#pragma unroll
    for (int nt = 0; nt < 8; ++nt) {
        const unsigned short* bp = W1T + (nt * 16 + l15) * 64 + quad * 8;
#pragma unroll
        for (int kk = 0; kk < 2; ++kk) {
            short8 bf = *reinterpret_cast<const short8*>(bp + kk * 32);
            acc[nt] = __builtin_amdgcn_mfma_f32_16x16x32_bf16(
                af[kk], bf, acc[nt], 0, 0, 0);
        }
    }

    const int lrow0 = wave * 16 + quad * 4;
#pragma unroll
    for (int nt = 0; nt < 8; ++nt) {
        float bb = b1 ? b1[nt * 16 + l15] : 0.f;
#pragma unroll
        for (int reg = 0; reg < 4; ++reg)
            Tb[(lrow0 + reg) * 136 + nt * 16 + l15] = f2b(acc[nt][reg] + bb);
    }
    __syncthreads();

#pragma unroll
    for (int p = 0; p < 4; ++p) {
        const int rloc = p * 16 + rgrp;
        const int r = base + rloc;
        if (r < M) {
            short8 hv = *reinterpret_cast<const short8*>(&Tb[rloc * 136 + c0]);
            *reinterpret_cast<short8*>(OUT0 + (size_t)r * 128 + c0) = hv;
        }
    }

    short8 af2[4];
#pragma unroll
    for (int kk = 0; kk < 4; ++kk)
        af2[kk] = *reinterpret_cast<const short8*>(
            &Tb[(wave * 16 + l15) * 136 + quad * 8 + kk * 32]);

    f32x4 acc2[8];
#pragma unroll
    for (int nt = 0; nt < 8; ++nt) acc2[nt] = (f32x4){0.f, 0.f, 0.f, 0.f};
#pragma unroll
    for (int nt = 0; nt < 8; ++nt) {
        const unsigned short* bp = W2T + (nt * 16 + l15) * 128 + quad * 8;
#pragma unroll
        for (int kk = 0; kk < 4; ++kk) {
            short8 bf = *reinterpret_cast<const short8*>(bp + kk * 32);
            acc2[nt] = __builtin_amdgcn_mfma_f32_16x16x32_bf16(
                af2[kk], bf, acc2[nt], 0, 0, 0);
        }
    }
#pragma unroll
    for (int nt = 0; nt < 8; ++nt)
#pragma unroll
        for (int reg = 0; reg < 4; ++reg)
            Tf[(lrow0 + reg) * 132 + nt * 16 + l15] = acc2[nt][reg];
    __syncthreads();
#pragma unroll
    for (int p = 0; p < 4; ++p) {
        const int rloc = p * 16 + rgrp;
        const int r = base + rloc;
        if (r >= M) continue;
        float4 u = *reinterpret_cast<const float4*>(&Tf[rloc * 132 + c0]);
        float4 v = *reinterpret_cast<const float4*>(&Tf[rloc * 132 + c0 + 4]);
        float o[8] = {u.x, u.y, u.z, u.w, v.x, v.y, v.z, v.w};
        short8 ov;
#pragma unroll
        for (int j = 0; j < 8; ++j) ov[j] = (short)f2b(o[j]);
        *reinterpret_cast<short8*>(OUT1 + (size_t)r * 128 + c0) = ov;
    }
}

// ---------------------------------------------------------------------------
// F2 with inline gather, both types in one launch.
// Phase G: gather mean rows (CSR over h_src) straight into the LDS tile.
// h1 = relu(mean@W1aT + A2@W1bT + b1)  (LDS only);  p2 = h1@W2T -> OUT1.
__global__ __launch_bounds__(256, 3) void fusedU2_both(
    const unsigned short* __restrict__ h_src,
    const int* __restrict__ offs_c, const int* __restrict__ eidx_c,
    const unsigned short* __restrict__ A2c,
    const unsigned short* __restrict__ W1aTc, const unsigned short* __restrict__ W1bTc,
    const float* __restrict__ b1c, const unsigned short* __restrict__ W2Tc,
    unsigned short* __restrict__ OUTc, int Mc, int nbc,
    const int* __restrict__ offs_m, const int* __restrict__ eidx_m,
    const unsigned short* __restrict__ A2m,
    const unsigned short* __restrict__ W1aTm, const unsigned short* __restrict__ W1bTm,
    const float* __restrict__ b1m, const unsigned short* __restrict__ W2Tm,
    unsigned short* __restrict__ OUTm, int Mm)
{
    __shared__ float Tf[64 * 132];
    __shared__ unsigned short Tb[64 * 136];
    const bool isC = (int)blockIdx.x < nbc;
    const int bx   = isC ? blockIdx.x : blockIdx.x - nbc;
    const int* offs = isC ? offs_c : offs_m;
    const int* eidx = isC ? eidx_c : eidx_m;
    const unsigned short* A2 = isC ? A2c : A2m;
    const unsigned short* W1aT = isC ? W1aTc : W1aTm;
    const unsigned short* W1bT = isC ? W1bTc : W1bTm;
    const float* b1 = isC ? b1c : b1m;
    const unsigned short* W2T = isC ? W2Tc : W2Tm;
    unsigned short* OUT1 = isC ? OUTc : OUTm;
    const int M = isC ? Mc : Mm;

    const int tid  = threadIdx.x;
    const int wave = tid >> 6;
    const int lane = tid & 63;
    const int quad = lane >> 4;
    const int l15  = lane & 15;
    const int base = bx * 64;
    const int rgrp = tid >> 4;
    const int c0   = l15 * 8;

    // Phase G: wave gathers its 16 dst nodes' mean rows into Tb (bf16)
    for (int n = 0; n < 16; ++n) {
        const int d = base + wave * 16 + n;
        int s = 0, e = 0;
        if (d < M) { s = offs[d]; e = offs[d + 1]; }
        float a[8] = {0.f, 0.f, 0.f, 0.f, 0.f, 0.f, 0.f, 0.f};
        for (int p = s + quad; p < e; p += 4) {
            int tx = eidx[p];
            short8 v = *reinterpret_cast<const short8*>(
                h_src + (size_t)tx * 128 + l15 * 8);
#pragma unroll
            for (int j = 0; j < 8; ++j) a[j] += b2f((unsigned short)v[j]);
        }
#pragma unroll
        for (int j = 0; j < 8; ++j) {
            a[j] += __shfl_xor(a[j], 16);
            a[j] += __shfl_xor(a[j], 32);
        }
        if (quad == 0 && d < M) {
            const float inv = (e > s) ? 1.0f / (float)(e - s) : 0.f;
            short8 o;
#pragma unroll
            for (int j = 0; j < 8; ++j) o[j] = (short)f2b(a[j] * inv);
            *reinterpret_cast<short8*>(&Tb[(wave * 16 + n) * 136 + l15 * 8]) = o;
        }
    }
    __syncthreads();

    // stage 1: mean (LDS) @ W1aT + h0 (global) @ W1bT
    short8 afa[4], afb[4];
    {
        int r = base + wave * 16 + l15;
        int rc = (r < M) ? r : 0;
        const unsigned short* a2 = A2 + (size_t)rc * 128 + quad * 8;
#pragma unroll
        for (int kk = 0; kk < 4; ++kk) {
            afa[kk] = *reinterpret_cast<const short8*>(
                &Tb[(wave * 16 + l15) * 136 + quad * 8 + kk * 32]);
            afb[kk] = *reinterpret_cast<const short8*>(a2 + kk * 32);
        }
    }

    f32x4 acc[8];
#pragma unroll
    for (int nt = 0; nt < 8; ++nt) acc[nt] = (f32x4){0.f, 0.f, 0.f, 0.f};
#pragma unroll
    for (int nt = 0; nt < 8; ++nt) {
        const unsigned short* bpa = W1aT + (nt * 16 + l15) * 128 + quad * 8;
        const unsigned short* bpb = W1bT + (nt * 16 + l15) * 128 + quad * 8;
#pragma unroll
        for (int kk = 0; kk < 4; ++kk) {
            short8 ba = *reinterpret_cast<const short8*>(bpa + kk * 32);
            acc[nt] = __builtin_amdgcn_mfma_f32_16x16x32_bf16(
                afa[kk], ba, acc[nt], 0, 0, 0);
            short8 bb = *reinterpret_cast<const short8*>(bpb + kk * 32);
            acc[nt] = __builtin_amdgcn_mfma_f32_16x16x32_bf16(
                afb[kk], bb, acc[nt], 0, 0, 0);
        }
    }
    __syncthreads();   // all waves done reading Tb (mean rows)

    const int lrow0 = wave * 16 + quad * 4;
#pragma unroll
    for (int nt = 0; nt < 8; ++nt) {
        float bv = b1 ? b1[nt * 16 + l15] : 0.f;
#pragma unroll
        for (int reg = 0; reg < 4; ++reg)
            Tb[(lrow0 + reg) * 136 + nt * 16 + l15] =
                f2b(fmaxf(acc[nt][reg] + bv, 0.f));
    }
    __syncthreads();

    short8 af2[4];
#pragma unroll
    for (int kk = 0; kk < 4; ++kk)
        af2[kk] = *reinterpret_cast<const short8*>(
            &Tb[(wave * 16 + l15) * 136 + quad * 8 + kk * 32]);

    f32x4 acc2[8];
#pragma unroll
    for (int nt = 0; nt < 8; ++nt) acc2[nt] = (f32x4){0.f, 0.f, 0.f, 0.f};
#pragma unroll
    for (int nt = 0; nt < 8; ++nt) {
        const unsigned short* bp = W2T + (nt * 16 + l15) * 128 + quad * 8;
#pragma unroll
        for (int kk = 0; kk < 4; ++kk) {
            short8 bf = *reinterpret_cast<const short8*>(bp + kk * 32);
            acc2[nt] = __builtin_amdgcn_mfma_f32_16x16x32_bf16(
                af2[kk], bf, acc2[nt], 0, 0, 0);
        }
    }
#pragma unroll
    for (int nt = 0; nt < 8; ++nt)
#pragma unroll
        for (int reg = 0; reg < 4; ++reg)
            Tf[(lrow0 + reg) * 132 + nt * 16 + l15] = acc2[nt][reg];
    __syncthreads();
#pragma unroll
    for (int p = 0; p < 4; ++p) {
        const int rloc = p * 16 + rgrp;
        const int r = base + rloc;
        if (r >= M) continue;
        float4 u = *reinterpret_cast<const float4*>(&Tf[rloc * 132 + c0]);
        float4 v = *reinterpret_cast<const float4*>(&Tf[rloc * 132 + c0 + 4]);
        float o[8] = {u.x, u.y, u.z, u.w, v.x, v.y, v.z, v.w};
        short8 ov;
#pragma unroll
        for (int j = 0; j < 8; ++j) ov[j] = (short)f2b(o[j]);
        *reinterpret_cast<short8*>(OUT1 + (size_t)r * 128 + c0) = ov;
    }
}

// ---------------------------------------------------------------------------
// Weight prep (unchanged): fp32 [K][128] -> bf16 transposed [128][K].
__global__ __launch_bounds__(256) void convert_weights(
    const float* __restrict__ tx_W, const float* __restrict__ card_proj_W,
    const float* __restrict__ merch_proj_W, const float* __restrict__ h1_W,
    const float* __restrict__ conv_Wl, const float* __restrict__ conv_Wr,
    const float* __restrict__ conv_bl,
    unsigned short* __restrict__ WT, float* __restrict__ bsum)
{
    int job = blockIdx.y;
    int K = 128;
    const float* src = nullptr;
    const float* src2 = nullptr;
    if (job == 0) src = tx_W;
    else if (job == 1) { src = card_proj_W; K = 64; }
    else if (job == 2) { src = merch_proj_W; K = 64; }
    else if (job == 3) src = h1_W;
    else {
        int l = (job - 4) / 7, e = (job - 4) % 7;
        const float* Wl = conv_Wl + (size_t)l * 4 * 16384;
        const float* Wr = conv_Wr + (size_t)l * 4 * 16384;
        switch (e) {
            case 0: src = Wl; break;
            case 1: src = Wl + 16384; break;
            case 2: src = Wl + 2 * 16384; break;
            case 3: src = Wl + 3 * 16384; break;
            case 4: src = Wr + 16384; break;
            case 5: src = Wr + 3 * 16384; break;
            default:
                src = Wr; src2 = Wr + 2 * 16384;
                if (blockIdx.x == 0 && threadIdx.x < 128) {
                    const float* bl = conv_bl + (size_t)l * 4 * 128;
                    bsum[l * 128 + threadIdx.x] =
                        bl[threadIdx.x] + bl[2 * 128 + threadIdx.x];
                }
                break;
        }
    }
    int e = blockIdx.x * 256 + threadIdx.x;
    if (e < (K << 7)) {
        int n = (K == 128) ? (e >> 7) : (e >> 6);
        int k = e & (K - 1);
        float v = src[(size_t)k * 128 + n];
        if (src2) v += src2[(size_t)k * 128 + n];
        WT[(size_t)job * 16384 + n * K + k] = f2b(v);
    }
}

// ---------------------------------------------------------------------------
// CSR build
__global__ __launch_bounds__(256) void hist_kernel(
    const int* __restrict__ e_card, const int* __restrict__ e_merch,
    int* __restrict__ hist_c, int* __restrict__ hist_m, int E)
{
    int i = blockIdx.x * 256 + threadIdx.x;
    if (i < E) {
        atomicAdd(&hist_c[e_card[i]], 1);
        atomicAdd(&hist_m[e_merch[i]], 1);
    }
}

// 2 blocks; 8 items/thread (7 barrier rounds for 50k instead of 49)
__global__ __launch_bounds__(1024) void scan2_kernel(
    const int* __restrict__ hist_c, int* __restrict__ offs_c, int* __restrict__ cur_c, int nc,
    const int* __restrict__ hist_m, int* __restrict__ offs_m, int* __restrict__ cur_m, int nm)
{
    const int* hist = (blockIdx.x == 0) ? hist_c : hist_m;
    int* offs = (blockIdx.x == 0) ? offs_c : offs_m;
    int* cursor = (blockIdx.x == 0) ? cur_c : cur_m;
    int n = (blockIdx.x == 0) ? nc : nm;
    __shared__ int wsum[16];
    __shared__ int s_carry;
    const int tid = threadIdx.x, lane = tid & 63, wid = tid >> 6;
    if (tid == 0) s_carry = 0;
    __syncthreads();
    for (int base = 0; base < n; base += 8192) {
        const int i0 = base + tid * 8;
        int v[8];
        int tot = 0;
#pragma unroll
        for (int j = 0; j < 8; ++j) {
            int idx = i0 + j;
            v[j] = (idx < n) ? hist[idx] : 0;
            tot += v[j];
        }
        int x = tot;
#pragma unroll
        for (int d = 1; d < 64; d <<= 1) {
            int t = __shfl_up(x, d);
            if (lane >= d) x += t;
        }
        if (lane == 63) wsum[wid] = x;
        __syncthreads();
        if (wid == 0) {
            int y = (lane < 16) ? wsum[lane] : 0;
#pragma unroll
            for (int d = 1; d < 16; d <<= 1) {
                int t = __shfl_up(y, d);
                if (lane >= d) y += t;
            }
            if (lane < 16) wsum[lane] = y;
        }
        __syncthreads();
        int wbase = (wid > 0) ? wsum[wid - 1] : 0;
        int run = s_carry + wbase + x - tot;
#pragma unroll
        for (int j = 0; j < 8; ++j) {
            int idx = i0 + j;
            if (idx < n) { offs[idx] = run; cursor[idx] = run; }
            run += v[j];
        }
        __syncthreads();
        if (tid == 0) s_carry += wsum[15];
        __syncthreads();
    }
    if (threadIdx.x == 0) offs[n] = s_carry;
}

__global__ __launch_bounds__(256) void place_kernel(
    const int* __restrict__ e_card, const int* __restrict__ e_tx_c,
    const int* __restrict__ e_merch, const int* __restrict__ e_tx_m,
    int* __restrict__ cur_c, int* __restrict__ eidx_c,
    int* __restrict__ cur_m, int* __restrict__ eidx_m, int E)
{
    int i = blockIdx.x * 256 + threadIdx.x;
    if (i < E) {
        int pc = atomicAdd(&cur_c[e_card[i]], 1);
        eidx_c[pc] = e_tx_c[i];
        int pm = atomicAdd(&cur_m[e_merch[i]], 1);
        eidx_m[pm] = e_tx_m[i];
    }
}

// ---------------------------------------------------------------------------
extern "C" void kernel_launch(void* const* d_in, const int* in_sizes, int n_in,
                              void* d_out, int out_size, void* d_ws, size_t ws_size,
                              hipStream_t stream)
{
    const float* tx_x        = (const float*)d_in[0];
    const int*   e_card      = (const int*)d_in[3];
    const int*   e_tx_c      = (const int*)d_in[4];
    const int*   e_merch     = (const int*)d_in[5];
    const int*   e_tx_m      = (const int*)d_in[6];
    const float* card_emb    = (const float*)d_in[7];
    const float* merch_emb   = (const float*)d_in[8];
    const float* card_proj_W = (const float*)d_in[9];
    const float* card_proj_b = (const float*)d_in[10];
    const float* merch_proj_W= (const float*)d_in[11];
    const float* merch_proj_b= (const float*)d_in[12];
    const float* tx_W        = (const float*)d_in[13];
    const float* tx_b        = (const float*)d_in[14];
    const float* conv_Wl     = (const float*)d_in[15];
    const float* conv_bl     = (const float*)d_in[16];
    const float* conv_Wr     = (const float*)d_in[17];
    const float* h1_W        = (const float*)d_in[18];
    const float* h1_b        = (const float*)d_in[19];
    const float* h2_W        = (const float*)d_in[20];
    const float* h2_b        = (const float*)d_in[21];

    char* wsb = (char*)d_ws;
    auto alloc = [&](size_t bytes) {
        char* p = wsb; wsb += (bytes + 255) & ~(size_t)255; return p;
    };
    unsigned short* h_tx0    = (unsigned short*)alloc((size_t)N_TX * 128 * 2);
    unsigned short* h_tx1    = (unsigned short*)alloc((size_t)N_TX * 128 * 2);
    unsigned short* h_card0  = (unsigned short*)alloc((size_t)N_CARD * 128 * 2);
    unsigned short* h_merch0 = (unsigned short*)alloc((size_t)N_MERCH * 128 * 2);
    unsigned short* p_card   = (unsigned short*)alloc((size_t)N_CARD * 128 * 2);
    unsigned short* p_merch  = (unsigned short*)alloc((size_t)N_MERCH * 128 * 2);
    unsigned short* WT       = (unsigned short*)alloc((size_t)18 * 16384 * 2);
    float* bsum = (float*)alloc(2 * 128 * 4);
    int* hist_c = (int*)alloc((size_t)(N_CARD + N_MERCH) * 4);  // one memset
    int* hist_m = hist_c + N_CARD;
    int* offs_c = (int*)alloc((size_t)(N_CARD + 1) * 4);
    int* cur_c  = (int*)alloc((size_t)N_CARD * 4);
    int* eidx_c = (int*)alloc((size_t)NE * 4);
    int* offs_m = (int*)alloc((size_t)(N_MERCH + 1) * 4);
    int* cur_m  = (int*)alloc((size_t)N_MERCH * 4);
    int* eidx_m = (int*)alloc((size_t)NE * 4);

    auto WTj = [&](int job) { return WT + (size_t)job * 16384; };

    const int nbc = (N_CARD + 63) / 64;
    const int nbm = (N_MERCH + 63) / 64;

    // weight prep + CSR build
    convert_weights<<<dim3(64, 18), dim3(256), 0, stream>>>(
        tx_W, card_proj_W, merch_proj_W, h1_W, conv_Wl, conv_Wr, conv_bl,
        WT, bsum);
    hipMemsetAsync(hist_c, 0, (size_t)(N_CARD + N_MERCH) * 4, stream);
    hist_kernel<<<dim3((NE + 255) / 256), dim3(256), 0, stream>>>(
        e_card, e_merch, hist_c, hist_m, NE);
    scan2_kernel<<<dim3(2), dim3(1024), 0, stream>>>(
        hist_c, offs_c, cur_c, N_CARD, hist_m, offs_m, cur_m, N_MERCH);
    place_kernel<<<dim3((NE + 255) / 256), dim3(256), 0, stream>>>(
        e_card, e_tx_c, e_merch, e_tx_m, cur_c, eidx_c, cur_m, eidx_m, NE);

    // F1: encoders + layer-1 p-projections, card+merch in one launch
    fusedE_both<<<dim3(nbc + nbm), dim3(256), 0, stream>>>(
        card_emb, WTj(1), card_proj_b, WTj(4), h_card0, p_card, N_CARD, nbc,
        merch_emb, WTj(2), merch_proj_b, WTj(6), h_merch0, p_merch, N_MERCH);

    // FUSED-A: tx encoder + layer-1 tx update
    fused2<<<dim3((N_TX + 63) / 64), dim3(256), 0, stream>>>(
        tx_x, 1, WTj(0), tx_b, WTj(10), bsum,
        p_card, e_card, p_merch, e_merch,
        h_tx0, nullptr, nullptr, h_tx1, N_TX);

    // F2 (+inline gather): layer-1 card/merch update + layer-2 p-projection.
    // mean gathered from h_tx0 straight into LDS; h1 never hits HBM;
    // p2 overwrites the dead p1 buffers.
    fusedU2_both<<<dim3(nbc + nbm), dim3(256), 0, stream>>>(
        h_tx0,
        offs_c, eidx_c, h_card0, WTj(5), WTj(8), conv_bl + 128, WTj(11),
        p_card, N_CARD, nbc,
        offs_m, eidx_m, h_merch0, WTj(7), WTj(9), conv_bl + 3 * 128, WTj(13),
        p_merch, N_MERCH);

    // FUSED-B: layer-2 tx update + head (h_tx2 never hits HBM)
    fused2<<<dim3((N_TX + 63) / 64), dim3(256), 0, stream>>>(
        h_tx1, 0, WTj(17), bsum + 128, WTj(3), h1_b,
        p_card, e_card, p_merch, e_merch,
        nullptr, h2_W, h2_b, d_out, N_TX);
}

// Round 9
// 659.600 us; speedup vs baseline: 1.0823x; 1.0823x over previous
//
#include <hip/hip_runtime.h>

// HeteroSAGE on MI355X — round 12: revert R11's inline-gather regression
// (675->714: serialized 16-node gather per wave vs gather_mean's 12.5k-block
// parallelism) + phase-legible profiling. fused2 split into template<MODE>
// instantiations (fused2k<0>=A, fused2k<1>=B) so rocprof shows each phase
// distinctly — fused2B/gathers/fusedU have never been measured individually.
// Kept from R11: merged fusedE_both/fusedU_both launches, 8-item scan.

#define N_TX    200000
#define N_CARD  50000
#define N_MERCH 10000
#define NE      200000

typedef __attribute__((ext_vector_type(8))) short short8;
typedef __attribute__((ext_vector_type(4))) float f32x4;

__device__ inline unsigned short f2b(float f) {
    unsigned u = __builtin_bit_cast(unsigned, f);
    unsigned r = (u + 0x7fffu + ((u >> 16) & 1u)) >> 16;   // RNE
    return (unsigned short)r;
}
__device__ inline float b2f(unsigned short s) {
    return __builtin_bit_cast(float, (unsigned)s << 16);
}

// ---------------------------------------------------------------------------
// Fused two-GEMM kernel (R8-proven). 64-row tiles, 4 waves.
// MODE 0 (A): h0 = relu(A@W1 + b1)                    -> store OUT0 (bf16)
//             out = relu(h0@W2 + b2 + P1[I1]+P2[I2])  -> OUT1 bf16
// MODE 1 (B): h  = relu(A@W1 + b1 + P1[I1]+P2[I2])    (LDS only)
//             out[r] = relu(h@W2 + b2) . h2w + h2b    -> OUT1 f32
template <int MODE>
__global__ __launch_bounds__(256, 3) void fused2k(
    const void* __restrict__ A, int a_f32,
    const unsigned short* __restrict__ W1T, const float* __restrict__ b1,
    const unsigned short* __restrict__ W2T, const float* __restrict__ b2,
    const unsigned short* __restrict__ P1, const int* __restrict__ I1,
    const unsigned short* __restrict__ P2, const int* __restrict__ I2,
    unsigned short* __restrict__ OUT0,
    const float* __restrict__ h2w, const float* __restrict__ h2b,
    void* __restrict__ OUT1, int M)
{
    constexpr bool modeA = (MODE == 0);
    __shared__ float Tf[64 * 132];            // fp32 transpose tile
    __shared__ unsigned short Tb[64 * 136];   // bf16 stage-2 A tile
    const int tid  = threadIdx.x;
    const int wave = tid >> 6;
    const int lane = tid & 63;
    const int quad = lane >> 4;
    const int l15  = lane & 15;
    const int base = blockIdx.x * 64;
    const int rgrp = tid >> 4;                // 0..15: row-pass row group
    const int c0   = l15 * 8;                 // row-pass column block

    int idx1[4], idx2[4];
#pragma unroll
    for (int p = 0; p < 4; ++p) {
        int r = base + p * 16 + rgrp;
        int rc = (r < M) ? r : 0;
        idx1[p] = I1 ? I1[rc] : 0;
        idx2[p] = I2 ? I2[rc] : 0;
    }

    short8 af[4];
    {
        int r = base + wave * 16 + l15;
        int rc = (r < M) ? r : 0;
        if (a_f32) {
            const float* ap = (const float*)A + (size_t)rc * 128 + quad * 8;
#pragma unroll
            for (int kk = 0; kk < 4; ++kk) {
                float4 u = *reinterpret_cast<const float4*>(ap + kk * 32);
                float4 v = *reinterpret_cast<const float4*>(ap + kk * 32 + 4);
                short8 t;
                t[0] = (short)f2b(u.x); t[1] = (short)f2b(u.y);
                t[2] = (short)f2b(u.z); t[3] = (short)f2b(u.w);
                t[4] = (short)f2b(v.x); t[5] = (short)f2b(v.y);
                t[6] = (short)f2b(v.z); t[7] = (short)f2b(v.w);
                af[kk] = t;
            }
        } else {
            const unsigned short* ap =
                (const unsigned short*)A + (size_t)rc * 128 + quad * 8;
#pragma unroll
            for (int kk = 0; kk < 4; ++kk)
                af[kk] = *reinterpret_cast<const short8*>(ap + kk * 32);
        }
    }

    f32x4 acc[8];
#pragma unroll
    for (int nt = 0; nt < 8; ++nt) acc[nt] = (f32x4){0.f, 0.f, 0.f, 0.f};
#pragma unroll
    for (int nt = 0; nt < 8; ++nt) {
        const unsigned short* bp = W1T + (nt * 16 + l15) * 128 + quad * 8;
#pragma unroll
        for (int kk = 0; kk < 4; ++kk) {
            short8 bf = *reinterpret_cast<const short8*>(bp + kk * 32);
            acc[nt] = __builtin_amdgcn_mfma_f32_16x16x32_bf16(
                af[kk], bf, acc[nt], 0, 0, 0);
        }
    }

    short8 p1v[4], p2v[4];
    if (P1) {
#pragma unroll
        for (int p = 0; p < 4; ++p)
            p1v[p] = *reinterpret_cast<const short8*>(
                P1 + (size_t)idx1[p] * 128 + c0);
    }
    if (P2) {
#pragma unroll
        for (int p = 0; p < 4; ++p)
            p2v[p] = *reinterpret_cast<const short8*>(
                P2 + (size_t)idx2[p] * 128 + c0);
    }

    const int lrow0 = wave * 16 + quad * 4;
    if (modeA) {
#pragma unroll
        for (int nt = 0; nt < 8; ++nt) {
            float bb = b1 ? b1[nt * 16 + l15] : 0.f;
#pragma unroll
            for (int reg = 0; reg < 4; ++reg)
                Tb[(lrow0 + reg) * 136 + nt * 16 + l15] =
                    f2b(fmaxf(acc[nt][reg] + bb, 0.f));
        }
    } else {
#pragma unroll
        for (int nt = 0; nt < 8; ++nt)
#pragma unroll
            for (int reg = 0; reg < 4; ++reg)
                Tf[(lrow0 + reg) * 132 + nt * 16 + l15] = acc[nt][reg];
    }
    __syncthreads();

    if (modeA) {
#pragma unroll
        for (int p = 0; p < 4; ++p) {
            const int rloc = p * 16 + rgrp;
            const int r = base + rloc;
            if (r < M) {
                short8 hv = *reinterpret_cast<const short8*>(&Tb[rloc * 136 + c0]);
                *reinterpret_cast<short8*>(OUT0 + (size_t)r * 128 + c0) = hv;
            }
        }
    } else {
        float b1r[8];
#pragma unroll
        for (int j = 0; j < 8; ++j) b1r[j] = b1 ? b1[c0 + j] : 0.f;
#pragma unroll
        for (int p = 0; p < 4; ++p) {
            const int rloc = p * 16 + rgrp;
            float4 u = *reinterpret_cast<const float4*>(&Tf[rloc * 132 + c0]);
            float4 v = *reinterpret_cast<const float4*>(&Tf[rloc * 132 + c0 + 4]);
            float o[8] = {u.x, u.y, u.z, u.w, v.x, v.y, v.z, v.w};
            short8 ov;
#pragma unroll
            for (int j = 0; j < 8; ++j) {
                float t = o[j] + b1r[j];
                if (P1) t += b2f((unsigned short)p1v[p][j]);
                if (P2) t += b2f((unsigned short)p2v[p][j]);
                ov[j] = (short)f2b(fmaxf(t, 0.f));
            }
            *reinterpret_cast<short8*>(&Tb[rloc * 136 + c0]) = ov;
        }
        __syncthreads();
    }

    short8 af2[4];
#pragma unroll
    for (int kk = 0; kk < 4; ++kk)
        af2[kk] = *reinterpret_cast<const short8*>(
            &Tb[(wave * 16 + l15) * 136 + quad * 8 + kk * 32]);

    f32x4 acc2[8];
#pragma unroll
    for (int nt = 0; nt < 8; ++nt) acc2[nt] = (f32x4){0.f, 0.f, 0.f, 0.f};
#pragma unroll
    for (int nt = 0; nt < 8; ++nt) {
        const unsigned short* bp = W2T + (nt * 16 + l15) * 128 + quad * 8;
#pragma unroll
        for (int kk = 0; kk < 4; ++kk) {
            short8 bf = *reinterpret_cast<const short8*>(bp + kk * 32);
            acc2[nt] = __builtin_amdgcn_mfma_f32_16x16x32_bf16(
                af2[kk], bf, acc2[nt], 0, 0, 0);
        }
    }

    if (!modeA) {
        float hsum[4] = {0.f, 0.f, 0.f, 0.f};
#pragma unroll
        for (int nt = 0; nt < 8; ++nt) {
            float bb = b2 ? b2[nt * 16 + l15] : 0.f;
            float w = h2w[nt * 16 + l15];
#pragma unroll
            for (int reg = 0; reg < 4; ++reg) {
                float o = fmaxf(acc2[nt][reg] + bb, 0.f);
                hsum[reg] += o * w;
            }
        }
        float* OUTf = (float*)OUT1;
#pragma unroll
        for (int reg = 0; reg < 4; ++reg) {
            float h = hsum[reg];
            h += __shfl_xor(h, 1);
            h += __shfl_xor(h, 2);
            h += __shfl_xor(h, 4);
            h += __shfl_xor(h, 8);
            int r = base + wave * 16 + quad * 4 + reg;
            if (l15 == 0 && r < M) OUTf[r] = h + h2b[0];
        }
    } else {
#pragma unroll
        for (int nt = 0; nt < 8; ++nt)
#pragma unroll
            for (int reg = 0; reg < 4; ++reg)
                Tf[(lrow0 + reg) * 132 + nt * 16 + l15] = acc2[nt][reg];
        __syncthreads();
        float b2r[8];
#pragma unroll
        for (int j = 0; j < 8; ++j) b2r[j] = b2 ? b2[c0 + j] : 0.f;
        unsigned short* OB = (unsigned short*)OUT1;
#pragma unroll
        for (int p = 0; p < 4; ++p) {
            const int rloc = p * 16 + rgrp;
            const int r = base + rloc;
            float4 u = *reinterpret_cast<const float4*>(&Tf[rloc * 132 + c0]);
            float4 v = *reinterpret_cast<const float4*>(&Tf[rloc * 132 + c0 + 4]);
            float o[8] = {u.x, u.y, u.z, u.w, v.x, v.y, v.z, v.w};
            short8 ov;
#pragma unroll
            for (int j = 0; j < 8; ++j) {
                float t = o[j] + b2r[j];
                if (P1) t += b2f((unsigned short)p1v[p][j]);
                if (P2) t += b2f((unsigned short)p2v[p][j]);
                ov[j] = (short)f2b(fmaxf(t, 0.f));
            }
            if (r < M)
                *reinterpret_cast<short8*>(OB + (size_t)r * 128 + c0) = ov;
        }
    }
}

// ---------------------------------------------------------------------------
// F1 both types in one launch: h0 = A(f32,[M][64])@W1T + b1 -> OUT0;
// p1 = h0@W2T -> OUT1. blockIdx < nbc -> card params, else merch.
__global__ __launch_bounds__(256, 3) void fusedE_both(
    const float* __restrict__ Ac, const unsigned short* __restrict__ W1Tc,
    const float* __restrict__ b1c, const unsigned short* __restrict__ W2Tc,
    unsigned short* __restrict__ OUT0c, unsigned short* __restrict__ OUT1c,
    int Mc, int nbc,
    const float* __restrict__ Am, const unsigned short* __restrict__ W1Tm,
    const float* __restrict__ b1m, const unsigned short* __restrict__ W2Tm,
    unsigned short* __restrict__ OUT0m, unsigned short* __restrict__ OUT1m,
    int Mm)
{
    __shared__ float Tf[64 * 132];
    __shared__ unsigned short Tb[64 * 136];
    const bool isC = (int)blockIdx.x < nbc;
    const int bx   = isC ? blockIdx.x : blockIdx.x - nbc;
    const float* A = isC ? Ac : Am;
    const unsigned short* W1T = isC ? W1Tc : W1Tm;
    const float* b1 = isC ? b1c : b1m;
    const unsigned short* W2T = isC ? W2Tc : W2Tm;
    unsigned short* OUT0 = isC ? OUT0c : OUT0m;
    unsigned short* OUT1 = isC ? OUT1c : OUT1m;
    const int M = isC ? Mc : Mm;

    const int tid  = threadIdx.x;
    const int wave = tid >> 6;
    const int lane = tid & 63;
    const int quad = lane >> 4;
    const int l15  = lane & 15;
    const int base = bx * 64;
    const int rgrp = tid >> 4;
    const int c0   = l15 * 8;

    short8 af[2];
    {
        int r = base + wave * 16 + l15;
        int rc = (r < M) ? r : 0;
        const float* ap = A + (size_t)rc * 64 + quad * 8;
#pragma unroll
        for (int kk = 0; kk < 2; ++kk) {
            float4 u = *reinterpret_cast<const float4*>(ap + kk * 32);
            float4 v = *reinterpret_cast<const float4*>(ap + kk * 32 + 4);
            short8 t;
            t[0] = (short)f2b(u.x); t[1] = (short)f2b(u.y);
            t[2] = (short)f2b(u.z); t[3] = (short)f2b(u.w);
            t[4] = (short)f2b(v.x); t[5] = (short)f2b(v.y);
            t[6] = (short)f2b(v.z); t[7] = (short)f2b(v.w);
            af[kk] = t;
        }
    }

    f32x4 acc[8];
#pragma unroll
    for (int nt = 0; nt < 8; ++nt) acc[nt] = (f32x4){0.f, 0.f, 0.f, 0.f};
#pragma unroll
    for (int nt = 0; nt < 8; ++nt) {
        const unsigned short* bp = W1T + (nt * 16 + l15) * 64 + quad * 8;
#pragma unroll
        for (int kk = 0; kk < 2; ++kk) {
            short8 bf = *reinterpret_cast<const short8*>(bp + kk * 32);
            acc[nt] = __builtin_amdgcn_mfma_f32_16x16x32_bf16(
                af[kk], bf, acc[nt], 0, 0, 0);
        }
    }

    const int lrow0 = wave * 16 + quad * 4;
#pragma unroll
    for (int nt = 0; nt < 8; ++nt) {
        float bb = b1 ? b1[nt * 16 + l15] : 0.f;
#pragma unroll
        for (int reg = 0; reg < 4; ++reg)
            Tb[(lrow0 + reg) * 136 + nt * 16 + l15] = f2b(acc[nt][reg] + bb);
    }
    __syncthreads();

#pragma unroll
    for (int p = 0; p < 4; ++p) {
        const int rloc = p * 16 + rgrp;
        const int r = base + rloc;
        if (r < M) {
            short8 hv = *reinterpret_cast<const short8*>(&Tb[rloc * 136 + c0]);
            *reinterpret_cast<short8*>(OUT0 + (size_t)r * 128 + c0) = hv;
        }
    }

    short8 af2[4];
#pragma unroll
    for (int kk = 0; kk < 4; ++kk)
        af2[kk] = *reinterpret_cast<const short8*>(
            &Tb[(wave * 16 + l15) * 136 + quad * 8 + kk * 32]);

    f32x4 acc2[8];
#pragma unroll
    for (int nt = 0; nt < 8; ++nt) acc2[nt] = (f32x4){0.f, 0.f, 0.f, 0.f};
#pragma unroll
    for (int nt = 0; nt < 8; ++nt) {
        const unsigned short* bp = W2T + (nt * 16 + l15) * 128 + quad * 8;
#pragma unroll
        for (int kk = 0; kk < 4; ++kk) {
            short8 bf = *reinterpret_cast<const short8*>(bp + kk * 32);
            acc2[nt] = __builtin_amdgcn_mfma_f32_16x16x32_bf16(
                af2[kk], bf, acc2[nt], 0, 0, 0);
        }
    }
#pragma unroll
    for (int nt = 0; nt < 8; ++nt)
#pragma unroll
        for (int reg = 0; reg < 4; ++reg)
            Tf[(lrow0 + reg) * 132 + nt * 16 + l15] = acc2[nt][reg];
    __syncthreads();
#pragma unroll
    for (int p = 0; p < 4; ++p) {
        const int rloc = p * 16 + rgrp;
        const int r = base + rloc;
        if (r >= M) continue;
        float4 u = *reinterpret_cast<const float4*>(&Tf[rloc * 132 + c0]);
        float4 v = *reinterpret_cast<const float4*>(&Tf[rloc * 132 + c0 + 4]);
        float o[8] = {u.x, u.y, u.z, u.w, v.x, v.y, v.z, v.w};
        short8 ov;
#pragma unroll
        for (int j = 0; j < 8; ++j) ov[j] = (short)f2b(o[j]);
        *reinterpret_cast<short8*>(OUT1 + (size_t)r * 128 + c0) = ov;
    }
}

// ---------------------------------------------------------------------------
// F2 both types in one launch (reads mean tables from HBM — R10 structure):
// h1 = relu(mean@W1aT + h0@W1bT + b1) (LDS only); p2 = h1@W2T -> OUT1.
__global__ __launch_bounds__(256, 3) void fusedU_both(
    const unsigned short* __restrict__ Mc_, const unsigned short* __restrict__ A2c,
    const unsigned short* __restrict__ W1aTc, const unsigned short* __restrict__ W1bTc,
    const float* __restrict__ b1c, const unsigned short* __restrict__ W2Tc,
    unsigned short* __restrict__ OUTc, int Mc, int nbc,
    const unsigned short* __restrict__ Mm_, const unsigned short* __restrict__ A2m,
    const unsigned short* __restrict__ W1aTm, const unsigned short* __restrict__ W1bTm,
    const float* __restrict__ b1m, const unsigned short* __restrict__ W2Tm,
    unsigned short* __restrict__ OUTm, int Mm)
{
    __shared__ float Tf[64 * 132];
    __shared__ unsigned short Tb[64 * 136];
    const bool isC = (int)blockIdx.x < nbc;
    const int bx   = isC ? blockIdx.x : blockIdx.x - nbc;
    const unsigned short* A1 = isC ? Mc_ : Mm_;
    const unsigned short* A2 = isC ? A2c : A2m;
    const unsigned short* W1aT = isC ? W1aTc : W1aTm;
    const unsigned short* W1bT = isC ? W1bTc : W1bTm;
    const float* b1 = isC ? b1c : b1m;
    const unsigned short* W2T = isC ? W2Tc : W2Tm;
    unsigned short* OUT1 = isC ? OUTc : OUTm;
    const int M = isC ? Mc : Mm;

    const int tid  = threadIdx.x;
    const int wave = tid >> 6;
    const int lane = tid & 63;
    const int quad = lane >> 4;
    const int l15  = lane & 15;
    const int base = bx * 64;
    const int rgrp = tid >> 4;
    const int c0   = l15 * 8;

    short8 afa[4], afb[4];
    {
        int r = base + wave * 16 + l15;
        int rc = (r < M) ? r : 0;
        const unsigned short* a1 = A1 + (size_t)rc * 128 + quad * 8;
        const unsigned short* a2 = A2 + (size_t)rc * 128 + quad * 8;
#pragma unroll
        for (int kk = 0; kk < 4; ++kk) {
            afa[kk] = *reinterpret_cast<const short8*>(a1 + kk * 32);
            afb[kk] = *reinterpret_cast<const short8*>(a2 + kk * 32);
        }
    }

    f32x4 acc[8];
#pragma unroll
    for (int nt = 0; nt < 8; ++nt) acc[nt] = (f32x4){0.f, 0.f, 0.f, 0.f};
#pragma unroll
    for (int nt = 0; nt < 8; ++nt) {
        const unsigned short* bpa = W1aT + (nt * 16 + l15) * 128 + quad * 8;
        const unsigned short* bpb = W1bT + (nt * 16 + l15) * 128 + quad * 8;
#pragma unroll
        for (int kk = 0; kk < 4; ++kk) {
            short8 ba = *reinterpret_cast<const short8*>(bpa + kk * 32);
            acc[nt] = __builtin_amdgcn_mfma_f32_16x16x32_bf16(
                afa[kk], ba, acc[nt], 0, 0, 0);
            short8 bb = *reinterpret_cast<const short8*>(bpb + kk * 32);
            acc[nt] = __builtin_amdgcn_mfma_f32_16x16x32_bf16(
                afb[kk], bb, acc[nt], 0, 0, 0);
        }
    }

    const int lrow0 = wave * 16 + quad * 4;
#pragma unroll
    for (int nt = 0; nt < 8; ++nt) {
        float bv = b1 ? b1[nt * 16 + l15] : 0.f;
#pragma unroll
        for (int reg = 0; reg < 4; ++reg)
            Tb[(lrow0 + reg) * 136 + nt * 16 + l15] =
                f2b(fmaxf(acc[nt][reg] + bv, 0.f));
    }
    __syncthreads();

    short8 af2[4];
#pragma unroll
    for (int kk = 0; kk < 4; ++kk)
        af2[kk] = *reinterpret_cast<const short8*>(
            &Tb[(wave * 16 + l15) * 136 + quad * 8 + kk * 32]);

    f32x4 acc2[8];
#pragma unroll
    for (int nt = 0; nt < 8; ++nt) acc2[nt] = (f32x4){0.f, 0.f, 0.f, 0.f};
#pragma unroll
    for (int nt = 0; nt < 8; ++nt) {
        const unsigned short* bp = W2T + (nt * 16 + l15) * 128 + quad * 8;
#pragma unroll
        for (int kk = 0; kk < 4; ++kk) {
            short8 bf = *reinterpret_cast<const short8*>(bp + kk * 32);
            acc2[nt] = __builtin_amdgcn_mfma_f32_16x16x32_bf16(
                af2[kk], bf, acc2[nt], 0, 0, 0);
        }
    }
#pragma unroll
    for (int nt = 0; nt < 8; ++nt)
#pragma unroll
        for (int reg = 0; reg < 4; ++reg)
            Tf[(lrow0 + reg) * 132 + nt * 16 + l15] = acc2[nt][reg];
    __syncthreads();
#pragma unroll
    for (int p = 0; p < 4; ++p) {
        const int rloc = p * 16 + rgrp;
        const int r = base + rloc;
        if (r >= M) continue;
        float4 u = *reinterpret_cast<const float4*>(&Tf[rloc * 132 + c0]);
        float4 v = *reinterpret_cast<const float4*>(&Tf[rloc * 132 + c0 + 4]);
        float o[8] = {u.x, u.y, u.z, u.w, v.x, v.y, v.z, v.w};
        short8 ov;
#pragma unroll
        for (int j = 0; j < 8; ++j) ov[j] = (short)f2b(o[j]);
        *reinterpret_cast<short8*>(OUT1 + (size_t)r * 128 + c0) = ov;
    }
}

// ---------------------------------------------------------------------------
// Weight prep: fp32 [K][128] -> bf16 transposed [128][K].
__global__ __launch_bounds__(256) void convert_weights(
    const float* __restrict__ tx_W, const float* __restrict__ card_proj_W,
    const float* __restrict__ merch_proj_W, const float* __restrict__ h1_W,
    const float* __restrict__ conv_Wl, const float* __restrict__ conv_Wr,
    const float* __restrict__ conv_bl,
    unsigned short* __restrict__ WT, float* __restrict__ bsum)
{
    int job = blockIdx.y;
    int K = 128;
    const float* src = nullptr;
    const float* src2 = nullptr;
    if (job == 0) src = tx_W;
    else if (job == 1) { src = card_proj_W; K = 64; }
    else if (job == 2) { src = merch_proj_W; K = 64; }
    else if (job == 3) src = h1_W;
    else {
        int l = (job - 4) / 7, e = (job - 4) % 7;
        const float* Wl = conv_Wl + (size_t)l * 4 * 16384;
        const float* Wr = conv_Wr + (size_t)l * 4 * 16384;
        switch (e) {
            case 0: src = Wl; break;
            case 1: src = Wl + 16384; break;
            case 2: src = Wl + 2 * 16384; break;
            case 3: src = Wl + 3 * 16384; break;
            case 4: src = Wr + 16384; break;
            case 5: src = Wr + 3 * 16384; break;
            default:
                src = Wr; src2 = Wr + 2 * 16384;
                if (blockIdx.x == 0 && threadIdx.x < 128) {
                    const float* bl = conv_bl + (size_t)l * 4 * 128;
                    bsum[l * 128 + threadIdx.x] =
                        bl[threadIdx.x] + bl[2 * 128 + threadIdx.x];
                }
                break;
        }
    }
    int e = blockIdx.x * 256 + threadIdx.x;
    if (e < (K << 7)) {
        int n = (K == 128) ? (e >> 7) : (e >> 6);
        int k = e & (K - 1);
        float v = src[(size_t)k * 128 + n];
        if (src2) v += src2[(size_t)k * 128 + n];
        WT[(size_t)job * 16384 + n * K + k] = f2b(v);
    }
}

// ---------------------------------------------------------------------------
// CSR build
__global__ __launch_bounds__(256) void hist_kernel(
    const int* __restrict__ e_card, const int* __restrict__ e_merch,
    int* __restrict__ hist_c, int* __restrict__ hist_m, int E)
{
    int i = blockIdx.x * 256 + threadIdx.x;
    if (i < E) {
        atomicAdd(&hist_c[e_card[i]], 1);
        atomicAdd(&hist_m[e_merch[i]], 1);
    }
}

// 2 blocks; 8 items/thread
__global__ __launch_bounds__(1024) void scan2_kernel(
    const int* __restrict__ hist_c, int* __restrict__ offs_c, int* __restrict__ cur_c, int nc,
    const int* __restrict__ hist_m, int* __restrict__ offs_m, int* __restrict__ cur_m, int nm)
{
    const int* hist = (blockIdx.x == 0) ? hist_c : hist_m;
    int* offs = (blockIdx.x == 0) ? offs_c : offs_m;
    int* cursor = (blockIdx.x == 0) ? cur_c : cur_m;
    int n = (blockIdx.x == 0) ? nc : nm;
    __shared__ int wsum[16];
    __shared__ int s_carry;
    const int tid = threadIdx.x, lane = tid & 63, wid = tid >> 6;
    if (tid == 0) s_carry = 0;
    __syncthreads();
    for (int base = 0; base < n; base += 8192) {
        const int i0 = base + tid * 8;
        int v[8];
        int tot = 0;
#pragma unroll
        for (int j = 0; j < 8; ++j) {
            int idx = i0 + j;
            v[j] = (idx < n) ? hist[idx] : 0;
            tot += v[j];
        }
        int x = tot;
#pragma unroll
        for (int d = 1; d < 64; d <<= 1) {
            int t = __shfl_up(x, d);
            if (lane >= d) x += t;
        }
        if (lane == 63) wsum[wid] = x;
        __syncthreads();
        if (wid == 0) {
            int y = (lane < 16) ? wsum[lane] : 0;
#pragma unroll
            for (int d = 1; d < 16; d <<= 1) {
                int t = __shfl_up(y, d);
                if (lane >= d) y += t;
            }
            if (lane < 16) wsum[lane] = y;
        }
        __syncthreads();
        int wbase = (wid > 0) ? wsum[wid - 1] : 0;
        int run = s_carry + wbase + x - tot;
#pragma unroll
        for (int j = 0; j < 8; ++j) {
            int idx = i0 + j;
            if (idx < n) { offs[idx] = run; cursor[idx] = run; }
            run += v[j];
        }
        __syncthreads();
        if (tid == 0) s_carry += wsum[15];
        __syncthreads();
    }
    if (threadIdx.x == 0) offs[n] = s_carry;
}

__global__ __launch_bounds__(256) void place_kernel(
    const int* __restrict__ e_card, const int* __restrict__ e_tx_c,
    const int* __restrict__ e_merch, const int* __restrict__ e_tx_m,
    int* __restrict__ cur_c, int* __restrict__ eidx_c,
    int* __restrict__ cur_m, int* __restrict__ eidx_m, int E)
{
    int i = blockIdx.x * 256 + threadIdx.x;
    if (i < E) {
        int pc = atomicAdd(&cur_c[e_card[i]], 1);
        eidx_c[pc] = e_tx_c[i];
        int pm = atomicAdd(&cur_m[e_merch[i]], 1);
        eidx_m[pm] = e_tx_m[i];
    }
}

// one wave per dst node (12.5k-block parallelism — measured-best form)
__global__ __launch_bounds__(256) void gather_mean(
    const unsigned short* __restrict__ h_src, const int* __restrict__ offs,
    const int* __restrict__ eidx, unsigned short* __restrict__ out_mean, int n_dst)
{
    const int lane = threadIdx.x & 63;
    const int l15 = lane & 15;
    const int quad = lane >> 4;
    const int d = blockIdx.x * 4 + (threadIdx.x >> 6);
    if (d >= n_dst) return;
    const int s = offs[d], e = offs[d + 1];
    float a[8] = {0.f, 0.f, 0.f, 0.f, 0.f, 0.f, 0.f, 0.f};
    for (int p = s + quad; p < e; p += 4) {
        int tx = eidx[p];
        short8 v = *reinterpret_cast<const short8*>(
            h_src + (size_t)tx * 128 + l15 * 8);
#pragma unroll
        for (int j = 0; j < 8; ++j) a[j] += b2f((unsigned short)v[j]);
    }
#pragma unroll
    for (int j = 0; j < 8; ++j) {
        a[j] += __shfl_xor(a[j], 16);
        a[j] += __shfl_xor(a[j], 32);
    }
    if (quad == 0) {
        const float inv = (e > s) ? 1.0f / (float)(e - s) : 0.f;
        short8 o;
#pragma unroll
        for (int j = 0; j < 8; ++j) o[j] = (short)f2b(a[j] * inv);
        *reinterpret_cast<short8*>(out_mean + (size_t)d * 128 + l15 * 8) = o;
    }
}

// ---------------------------------------------------------------------------
extern "C" void kernel_launch(void* const* d_in, const int* in_sizes, int n_in,
                              void* d_out, int out_size, void* d_ws, size_t ws_size,
                              hipStream_t stream)
{
    const float* tx_x        = (const float*)d_in[0];
    const int*   e_card      = (const int*)d_in[3];
    const int*   e_tx_c      = (const int*)d_in[4];
    const int*   e_merch     = (const int*)d_in[5];
    const int*   e_tx_m      = (const int*)d_in[6];
    const float* card_emb    = (const float*)d_in[7];
    const float* merch_emb   = (const float*)d_in[8];
    const float* card_proj_W = (const float*)d_in[9];
    const float* card_proj_b = (const float*)d_in[10];
    const float* merch_proj_W= (const float*)d_in[11];
    const float* merch_proj_b= (const float*)d_in[12];
    const float* tx_W        = (const float*)d_in[13];
    const float* tx_b        = (const float*)d_in[14];
    const float* conv_Wl     = (const float*)d_in[15];
    const float* conv_bl     = (const float*)d_in[16];
    const float* conv_Wr     = (const float*)d_in[17];
    const float* h1_W        = (const float*)d_in[18];
    const float* h1_b        = (const float*)d_in[19];
    const float* h2_W        = (const float*)d_in[20];
    const float* h2_b        = (const float*)d_in[21];

    char* wsb = (char*)d_ws;
    auto alloc = [&](size_t bytes) {
        char* p = wsb; wsb += (bytes + 255) & ~(size_t)255; return p;
    };
    unsigned short* h_tx0      = (unsigned short*)alloc((size_t)N_TX * 128 * 2);
    unsigned short* h_tx1      = (unsigned short*)alloc((size_t)N_TX * 128 * 2);
    unsigned short* h_card0    = (unsigned short*)alloc((size_t)N_CARD * 128 * 2);
    unsigned short* h_merch0   = (unsigned short*)alloc((size_t)N_MERCH * 128 * 2);
    unsigned short* p_card     = (unsigned short*)alloc((size_t)N_CARD * 128 * 2);
    unsigned short* p_merch    = (unsigned short*)alloc((size_t)N_MERCH * 128 * 2);
    unsigned short* mean_card  = (unsigned short*)alloc((size_t)N_CARD * 128 * 2);
    unsigned short* mean_merch = (unsigned short*)alloc((size_t)N_MERCH * 128 * 2);
    unsigned short* WT         = (unsigned short*)alloc((size_t)18 * 16384 * 2);
    float* bsum = (float*)alloc(2 * 128 * 4);
    int* hist_c = (int*)alloc((size_t)(N_CARD + N_MERCH) * 4);  // one memset
    int* hist_m = hist_c + N_CARD;
    int* offs_c = (int*)alloc((size_t)(N_CARD + 1) * 4);
    int* cur_c  = (int*)alloc((size_t)N_CARD * 4);
    int* eidx_c = (int*)alloc((size_t)NE * 4);
    int* offs_m = (int*)alloc((size_t)(N_MERCH + 1) * 4);
    int* cur_m  = (int*)alloc((size_t)N_MERCH * 4);
    int* eidx_m = (int*)alloc((size_t)NE * 4);

    auto WTj = [&](int job) { return WT + (size_t)job * 16384; };

    const int nbc = (N_CARD + 63) / 64;
    const int nbm = (N_MERCH + 63) / 64;

    // weight prep + CSR build
    convert_weights<<<dim3(64, 18), dim3(256), 0, stream>>>(
        tx_W, card_proj_W, merch_proj_W, h1_W, conv_Wl, conv_Wr, conv_bl,
        WT, bsum);
    hipMemsetAsync(hist_c, 0, (size_t)(N_CARD + N_MERCH) * 4, stream);
    hist_kernel<<<dim3((NE + 255) / 256), dim3(256), 0, stream>>>(
        e_card, e_merch, hist_c, hist_m, NE);
    scan2_kernel<<<dim3(2), dim3(1024), 0, stream>>>(
        hist_c, offs_c, cur_c, N_CARD, hist_m, offs_m, cur_m, N_MERCH);
    place_kernel<<<dim3((NE + 255) / 256), dim3(256), 0, stream>>>(
        e_card, e_tx_c, e_merch, e_tx_m, cur_c, eidx_c, cur_m, eidx_m, NE);

    // F1: encoders + layer-1 p-projections (card+merch, one launch)
    fusedE_both<<<dim3(nbc + nbm), dim3(256), 0, stream>>>(
        card_emb, WTj(1), card_proj_b, WTj(4), h_card0, p_card, N_CARD, nbc,
        merch_emb, WTj(2), merch_proj_b, WTj(6), h_merch0, p_merch, N_MERCH);

    // FUSED-A: tx encoder + layer-1 tx update
    fused2k<0><<<dim3((N_TX + 63) / 64), dim3(256), 0, stream>>>(
        tx_x, 1, WTj(0), tx_b, WTj(10), bsum,
        p_card, e_card, p_merch, e_merch,
        h_tx0, nullptr, nullptr, h_tx1, N_TX);

    // layer-1 aggregation (1 wave/node; reads h_tx0)
    gather_mean<<<dim3((N_CARD + 3) / 4), dim3(256), 0, stream>>>(
        h_tx0, offs_c, eidx_c, mean_card, N_CARD);
    gather_mean<<<dim3((N_MERCH + 3) / 4), dim3(256), 0, stream>>>(
        h_tx0, offs_m, eidx_m, mean_merch, N_MERCH);

    // F2: layer-1 card/merch update + layer-2 p-projection (one launch);
    // h1 stays in LDS; p2 overwrites dead p1 buffers.
    fusedU_both<<<dim3(nbc + nbm), dim3(256), 0, stream>>>(
        mean_card, h_card0, WTj(5), WTj(8), conv_bl + 128, WTj(11),
        p_card, N_CARD, nbc,
        mean_merch, h_merch0, WTj(7), WTj(9), conv_bl + 3 * 128, WTj(13),
        p_merch, N_MERCH);

    // FUSED-B: layer-2 tx update + head (h_tx2 never hits HBM)
    fused2k<1><<<dim3((N_TX + 63) / 64), dim3(256), 0, stream>>>(
        h_tx1, 0, WTj(17), bsum + 128, WTj(3), h1_b,
        p_card, e_card, p_merch, e_merch,
        nullptr, h2_W, h2_b, d_out, N_TX);
}